// Round 1
// baseline (576.450 us; speedup 1.0000x reference)
//
#include <hip/hip_runtime.h>
#include <hip/hip_bf16.h>
#include <stdint.h>

#define BATCH 4
#define SEQ   2048
#define EMB   1024
#define NHEAD 16
#define HDIM  64

typedef __bf16 bf16x8 __attribute__((ext_vector_type(8)));
typedef float  f32x4  __attribute__((ext_vector_type(4)));

// ---------------- fp32 -> bf16 cast, 4 elems/thread ----------------
__global__ __launch_bounds__(256) void cvt_f32_bf16(const float* __restrict__ in,
                                                    __bf16* __restrict__ out, int n4) {
  int i = blockIdx.x * 256 + threadIdx.x;
  if (i >= n4) return;
  float4 v = reinterpret_cast<const float4*>(in)[i];
  union { ushort4 u; __bf16 b[4]; } o;
  o.b[0] = (__bf16)v.x; o.b[1] = (__bf16)v.y;
  o.b[2] = (__bf16)v.z; o.b[3] = (__bf16)v.w;
  reinterpret_cast<ushort4*>(out)[i] = o.u;
}

// ---------------- bf16 GEMM: C = A * Bt^T + bias ----------------
// A: M x K row-major bf16; Bt: N x K row-major bf16 (i.e. torch Linear weight)
// 128x128 tile, 256 threads (4 waves, 2x2), BK=32, mfma_f32_16x16x32_bf16.
enum { EPI_BF16 = 0, EPI_F32 = 1, EPI_VT = 2 };

__device__ __forceinline__ void gload_lds16(const void* g, void* l) {
  __builtin_amdgcn_global_load_lds((const uint32_t __attribute__((address_space(1)))*)g,
                                   (uint32_t __attribute__((address_space(3)))*)l, 16, 0, 0);
}

template <int MODE>
__global__ __launch_bounds__(256, 2)
void gemm_bt(const __bf16* __restrict__ A, const __bf16* __restrict__ Bt,
             const float* __restrict__ bias, void* __restrict__ Cout,
             int M, int N, int K) {
  __shared__ __bf16 As[128 * 32];
  __shared__ __bf16 Bs[128 * 32];
  const int tid  = threadIdx.x;
  const int wave = tid >> 6, lane = tid & 63;
  const int l4 = lane >> 4, l15 = lane & 15;
  const int row0 = blockIdx.x * 128, col0 = blockIdx.y * 128;
  const int wr = (wave >> 1) * 64, wc = (wave & 1) * 64;

  // staging map: LDS byte = wave*1024 + lane*16 (+i*4096) -> row-major [128][32] bf16
  const int srow = wave * 16 + (lane >> 2);
  const int scol = (lane & 3) * 8;

  f32x4 acc[4][4] = {};

  const __bf16* ga = A  + (size_t)(row0 + srow) * K + scol;
  const __bf16* gb = Bt + (size_t)(col0 + srow) * K + scol;
  char* lA = (char*)As + wave * 1024;
  char* lB = (char*)Bs + wave * 1024;

  for (int k0 = 0; k0 < K; k0 += 32) {
    __syncthreads();                       // prior tile's reads complete
    gload_lds16(ga + k0, lA);
    gload_lds16(ga + k0 + (size_t)64 * K, lA + 4096);
    gload_lds16(gb + k0, lB);
    gload_lds16(gb + k0 + (size_t)64 * K, lB + 4096);
    __syncthreads();                       // vmcnt drained before barrier by compiler

    bf16x8 af[4], bfv[4];
#pragma unroll
    for (int m = 0; m < 4; ++m)
      af[m] = *(const bf16x8*)((const char*)As + (wr + m * 16 + l15) * 64 + l4 * 16);
#pragma unroll
    for (int n = 0; n < 4; ++n)
      bfv[n] = *(const bf16x8*)((const char*)Bs + (wc + n * 16 + l15) * 64 + l4 * 16);
#pragma unroll
    for (int m = 0; m < 4; ++m)
#pragma unroll
      for (int n = 0; n < 4; ++n)
        acc[m][n] = __builtin_amdgcn_mfma_f32_16x16x32_bf16(af[m], bfv[n], acc[m][n], 0, 0, 0);
  }

  // epilogue: D elem (row=(lane>>4)*4+i, col=lane&15) per 16x16 frag
#pragma unroll
  for (int m = 0; m < 4; ++m) {
    const int r = row0 + wr + m * 16 + l4 * 4;
#pragma unroll
    for (int n = 0; n < 4; ++n) {
      const int c  = col0 + wc + n * 16 + l15;
      const float bb = bias[c];
      if (MODE == EPI_F32) {
        float* C = (float*)Cout;
#pragma unroll
        for (int i = 0; i < 4; ++i) C[(size_t)(r + i) * N + c] = acc[m][n][i] + bb;
      } else if (MODE == EPI_BF16) {
        __bf16* C = (__bf16*)Cout;
#pragma unroll
        for (int i = 0; i < 4; ++i) C[(size_t)(r + i) * N + c] = (__bf16)(acc[m][n][i] + bb);
      } else {  // EPI_VT: write V^T as [b][h][d][s]; r = b*SEQ+s, c = h*HDIM+d
        const int b = r >> 11, s = r & (SEQ - 1);
        const int h = c >> 6, d = c & (HDIM - 1);
        union { ushort4 u; __bf16 x[4]; } o;
#pragma unroll
        for (int i = 0; i < 4; ++i) o.x[i] = (__bf16)(acc[m][n][i] + bb);
        *(ushort4*)((__bf16*)Cout + ((size_t)((b * NHEAD + h) * HDIM + d)) * SEQ + s) = o.u;
      }
    }
  }
}

// ---------------- flash attention ----------------
// grid (SEQ/64, BATCH*NHEAD), 256 threads. Wave w owns Q rows [qtile*64+w*16, +16).
// Q: [b][s][h*64+d] bf16, K: same, Vt: [b][h][d][s] bf16. O: [b][s][h*64+d] bf16.
__global__ __launch_bounds__(256, 2)
void attn_fwd(const __bf16* __restrict__ Q, const __bf16* __restrict__ Kk,
              const __bf16* __restrict__ Vt, __bf16* __restrict__ O) {
  __shared__ __bf16 Ks[32][72];      // padded: 144B rows (16B aligned, banks spread)
  __shared__ __bf16 Vs[64][40];      // padded: 80B rows
  __shared__ __bf16 Ps[4][16][40];   // per-wave P tile, padded

  const int tid  = threadIdx.x;
  const int wave = tid >> 6, lane = tid & 63;
  const int l4 = lane >> 4, l15 = lane & 15;
  const int bh = blockIdx.y;
  const int b = bh >> 4, h = bh & 15;
  const int q0 = blockIdx.x * 64 + wave * 16;

  // Q fragments for the wave's 16 rows, D=64 -> 2 MFMA k-steps
  const __bf16* qbase = Q + (size_t)(b * SEQ + q0 + l15) * EMB + h * HDIM;
  bf16x8 aq[2];
  aq[0] = *(const bf16x8*)(qbase + l4 * 8);
  aq[1] = *(const bf16x8*)(qbase + 32 + l4 * 8);

  f32x4 oacc[4] = {};
  float mx[4], ls[4];
#pragma unroll
  for (int i = 0; i < 4; ++i) { mx[i] = -1e30f; ls[i] = 0.f; }

  const __bf16* kgbase = Kk + (size_t)(b * SEQ) * EMB + h * HDIM;
  const __bf16* vgbase = Vt + (size_t)((b * NHEAD + h) * HDIM) * SEQ;

  const int krow = tid >> 3, kcol = (tid & 7) * 8;  // K tile: 32 keys x 64 d
  const int vrow = tid >> 2, vcol = (tid & 3) * 8;  // Vt tile: 64 d x 32 keys

  for (int kt = 0; kt < SEQ; kt += 32) {
    bf16x8 kreg = *(const bf16x8*)(kgbase + (size_t)(kt + krow) * EMB + kcol);
    bf16x8 vreg = *(const bf16x8*)(vgbase + (size_t)vrow * SEQ + kt + vcol);
    __syncthreads();                      // prior tile's reads complete
    *(bf16x8*)(&Ks[krow][kcol]) = kreg;
    *(bf16x8*)(&Vs[vrow][vcol]) = vreg;
    __syncthreads();

    // S = Q K^T  (16 q x 32 keys per wave)
    f32x4 sc[2] = {};
#pragma unroll
    for (int n = 0; n < 2; ++n)
#pragma unroll
      for (int kk = 0; kk < 2; ++kk) {
        bf16x8 kf = *(const bf16x8*)((const char*)&Ks[n * 16 + l15][0] + kk * 64 + l4 * 16);
        sc[n] = __builtin_amdgcn_mfma_f32_16x16x32_bf16(aq[kk], kf, sc[n], 0, 0, 0);
      }

    // online softmax (rows r=(lane>>4)*4+i live in 16-lane groups)
    float pm[4];
#pragma unroll
    for (int i = 0; i < 4; ++i) {
      sc[0][i] *= 0.125f; sc[1][i] *= 0.125f;
      pm[i] = fmaxf(sc[0][i], sc[1][i]);
      pm[i] = fmaxf(pm[i], __shfl_xor(pm[i], 1));
      pm[i] = fmaxf(pm[i], __shfl_xor(pm[i], 2));
      pm[i] = fmaxf(pm[i], __shfl_xor(pm[i], 4));
      pm[i] = fmaxf(pm[i], __shfl_xor(pm[i], 8));
    }
    float corr[4], rs[4];
#pragma unroll
    for (int i = 0; i < 4; ++i) {
      float mn = fmaxf(mx[i], pm[i]);
      corr[i] = __expf(mx[i] - mn);
      mx[i] = mn;
      float p0 = __expf(sc[0][i] - mn);
      float p1 = __expf(sc[1][i] - mn);
      rs[i] = p0 + p1;
      Ps[wave][l4 * 4 + i][l15]      = (__bf16)p0;
      Ps[wave][l4 * 4 + i][16 + l15] = (__bf16)p1;
    }
#pragma unroll
    for (int i = 0; i < 4; ++i) {
      rs[i] += __shfl_xor(rs[i], 1);
      rs[i] += __shfl_xor(rs[i], 2);
      rs[i] += __shfl_xor(rs[i], 4);
      rs[i] += __shfl_xor(rs[i], 8);
      ls[i] = ls[i] * corr[i] + rs[i];
    }
#pragma unroll
    for (int n = 0; n < 4; ++n)
#pragma unroll
      for (int i = 0; i < 4; ++i) oacc[n][i] *= corr[i];

    // PV: A = P (via wave-local LDS relayout), B = V^T tile (contiguous b128)
    bf16x8 pa = *(const bf16x8*)((const char*)&Ps[wave][l15][0] + l4 * 16);
#pragma unroll
    for (int n = 0; n < 4; ++n) {
      bf16x8 bv = *(const bf16x8*)((const char*)&Vs[n * 16 + l15][0] + l4 * 16);
      oacc[n] = __builtin_amdgcn_mfma_f32_16x16x32_bf16(pa, bv, oacc[n], 0, 0, 0);
    }
  }

  // normalize and store
  __bf16* obase = O + (size_t)(b * SEQ + q0 + l4 * 4) * EMB + h * HDIM;
#pragma unroll
  for (int i = 0; i < 4; ++i) {
    float inv = 1.f / ls[i];
#pragma unroll
    for (int n = 0; n < 4; ++n)
      obase[(size_t)i * EMB + n * 16 + l15] = (__bf16)(oacc[n][i] * inv);
  }
}

// ---------------- launch ----------------
extern "C" void kernel_launch(void* const* d_in, const int* in_sizes, int n_in,
                              void* d_out, int out_size, void* d_ws, size_t ws_size,
                              hipStream_t stream) {
  const float* query = (const float*)d_in[0];
  const float* key   = (const float*)d_in[1];
  const float* value = (const float*)d_in[2];
  const float* Wq = (const float*)d_in[3]; const float* bq = (const float*)d_in[4];
  const float* Wk = (const float*)d_in[5]; const float* bk = (const float*)d_in[6];
  const float* Wv = (const float*)d_in[7]; const float* bv = (const float*)d_in[8];
  const float* Wo = (const float*)d_in[9]; const float* bo = (const float*)d_in[10];

  char* ws = (char*)d_ws;
  const size_t MB = 1u << 20;
  __bf16* Xb  = (__bf16*)(ws);             // 16 MB staging (also reused for attn out)
  __bf16* Qb  = (__bf16*)(ws + 16 * MB);
  __bf16* Kb  = (__bf16*)(ws + 32 * MB);
  __bf16* Vt  = (__bf16*)(ws + 48 * MB);
  __bf16* Wqb = (__bf16*)(ws + 64 * MB);
  __bf16* Wkb = (__bf16*)(ws + 66 * MB);
  __bf16* Wvb = (__bf16*)(ws + 68 * MB);
  __bf16* Wob = (__bf16*)(ws + 70 * MB);

  const int NE = BATCH * SEQ * EMB;   // 8388608
  const int NW = EMB * EMB;           // 1048576
  const int M = BATCH * SEQ;

  dim3 blk(256);
  dim3 gg(M / 128, EMB / 128);

  cvt_f32_bf16<<<dim3(NW / 4 / 256), blk, 0, stream>>>(Wq, Wqb, NW / 4);
  cvt_f32_bf16<<<dim3(NW / 4 / 256), blk, 0, stream>>>(Wk, Wkb, NW / 4);
  cvt_f32_bf16<<<dim3(NW / 4 / 256), blk, 0, stream>>>(Wv, Wvb, NW / 4);
  cvt_f32_bf16<<<dim3(NW / 4 / 256), blk, 0, stream>>>(Wo, Wob, NW / 4);

  cvt_f32_bf16<<<dim3(NE / 4 / 256), blk, 0, stream>>>(query, Xb, NE / 4);
  gemm_bt<EPI_BF16><<<gg, blk, 0, stream>>>(Xb, Wqb, bq, Qb, M, EMB, EMB);
  cvt_f32_bf16<<<dim3(NE / 4 / 256), blk, 0, stream>>>(key, Xb, NE / 4);
  gemm_bt<EPI_BF16><<<gg, blk, 0, stream>>>(Xb, Wkb, bk, Kb, M, EMB, EMB);
  cvt_f32_bf16<<<dim3(NE / 4 / 256), blk, 0, stream>>>(value, Xb, NE / 4);
  gemm_bt<EPI_VT><<<gg, blk, 0, stream>>>(Xb, Wvb, bv, Vt, M, EMB, EMB);

  attn_fwd<<<dim3(SEQ / 64, BATCH * NHEAD), blk, 0, stream>>>(Qb, Kb, Vt, Xb);

  gemm_bt<EPI_F32><<<gg, blk, 0, stream>>>(Xb, Wob, bo, d_out, M, EMB, EMB);
}

// Round 2
// 383.241 us; speedup vs baseline: 1.5041x; 1.5041x over previous
//
#include <hip/hip_runtime.h>
#include <hip/hip_bf16.h>
#include <stdint.h>

#define BATCH 4
#define SEQ   2048
#define EMB   1024
#define NHEAD 16
#define HDIM  64

typedef __bf16 bf16x8 __attribute__((ext_vector_type(8)));
typedef float  f32x4  __attribute__((ext_vector_type(4)));
typedef float  f32x16 __attribute__((ext_vector_type(16)));

// ---------------- fp32 -> bf16 cast, 4 elems/thread ----------------
__global__ __launch_bounds__(256) void cvt_f32_bf16(const float* __restrict__ in,
                                                    __bf16* __restrict__ out, int n4) {
  int i = blockIdx.x * 256 + threadIdx.x;
  if (i >= n4) return;
  float4 v = reinterpret_cast<const float4*>(in)[i];
  union { ushort4 u; __bf16 b[4]; } o;
  o.b[0] = (__bf16)v.x; o.b[1] = (__bf16)v.y;
  o.b[2] = (__bf16)v.z; o.b[3] = (__bf16)v.w;
  reinterpret_cast<ushort4*>(out)[i] = o.u;
}

__device__ __forceinline__ void gload_lds16(const void* g, void* l) {
  __builtin_amdgcn_global_load_lds((const uint32_t __attribute__((address_space(1)))*)g,
                                   (uint32_t __attribute__((address_space(3)))*)l, 16, 0, 0);
}

// ---------------- bf16 GEMM: C = A * Bt^T + bias (unchanged, known-good) ----------------
enum { EPI_BF16 = 0, EPI_F32 = 1, EPI_VT = 2 };

template <int MODE>
__global__ __launch_bounds__(256, 2)
void gemm_bt(const __bf16* __restrict__ A, const __bf16* __restrict__ Bt,
             const float* __restrict__ bias, void* __restrict__ Cout,
             int M, int N, int K) {
  __shared__ __bf16 As[128 * 32];
  __shared__ __bf16 Bs[128 * 32];
  const int tid  = threadIdx.x;
  const int wave = tid >> 6, lane = tid & 63;
  const int l4 = lane >> 4, l15 = lane & 15;
  const int row0 = blockIdx.x * 128, col0 = blockIdx.y * 128;
  const int wr = (wave >> 1) * 64, wc = (wave & 1) * 64;

  const int srow = wave * 16 + (lane >> 2);
  const int scol = (lane & 3) * 8;

  f32x4 acc[4][4] = {};

  const __bf16* ga = A  + (size_t)(row0 + srow) * K + scol;
  const __bf16* gb = Bt + (size_t)(col0 + srow) * K + scol;
  char* lA = (char*)As + wave * 1024;
  char* lB = (char*)Bs + wave * 1024;

  for (int k0 = 0; k0 < K; k0 += 32) {
    __syncthreads();
    gload_lds16(ga + k0, lA);
    gload_lds16(ga + k0 + (size_t)64 * K, lA + 4096);
    gload_lds16(gb + k0, lB);
    gload_lds16(gb + k0 + (size_t)64 * K, lB + 4096);
    __syncthreads();

    bf16x8 af[4], bfv[4];
#pragma unroll
    for (int m = 0; m < 4; ++m)
      af[m] = *(const bf16x8*)((const char*)As + (wr + m * 16 + l15) * 64 + l4 * 16);
#pragma unroll
    for (int n = 0; n < 4; ++n)
      bfv[n] = *(const bf16x8*)((const char*)Bs + (wc + n * 16 + l15) * 64 + l4 * 16);
#pragma unroll
    for (int m = 0; m < 4; ++m)
#pragma unroll
      for (int n = 0; n < 4; ++n)
        acc[m][n] = __builtin_amdgcn_mfma_f32_16x16x32_bf16(af[m], bfv[n], acc[m][n], 0, 0, 0);
  }

#pragma unroll
  for (int m = 0; m < 4; ++m) {
    const int r = row0 + wr + m * 16 + l4 * 4;
#pragma unroll
    for (int n = 0; n < 4; ++n) {
      const int c  = col0 + wc + n * 16 + l15;
      const float bb = bias[c];
      if (MODE == EPI_F32) {
        float* C = (float*)Cout;
#pragma unroll
        for (int i = 0; i < 4; ++i) C[(size_t)(r + i) * N + c] = acc[m][n][i] + bb;
      } else if (MODE == EPI_BF16) {
        __bf16* C = (__bf16*)Cout;
#pragma unroll
        for (int i = 0; i < 4; ++i) C[(size_t)(r + i) * N + c] = (__bf16)(acc[m][n][i] + bb);
      } else {  // EPI_VT: write V^T as [b][h][d][s]
        const int b = r >> 11, s = r & (SEQ - 1);
        const int h = c >> 6, d = c & (HDIM - 1);
        union { ushort4 u; __bf16 x[4]; } o;
#pragma unroll
        for (int i = 0; i < 4; ++i) o.x[i] = (__bf16)(acc[m][n][i] + bb);
        *(ushort4*)((__bf16*)Cout + ((size_t)((b * NHEAD + h) * HDIM + d)) * SEQ + s) = o.u;
      }
    }
  }
}

// ---------------- flash attention v2: swapped-QK^T, 32x32 MFMA ----------------
// grid (B*H=64, SEQ/256=8), 512 threads (8 waves x 32 q-rows).
// Q,K: [b][s][h*64+d] bf16; Vt: [b][h][d][s] bf16; O: [b][s][h*64+d] bf16.
// Per KV tile (64 keys): sc = mfma(K, Q) -> S^T (col=q=lane&31); softmax per-lane;
// P relayout in-register (pack + shfl_xor 32); O^T = mfma(Vt, P^T) accumulate.
__device__ __forceinline__ f32x16 mfma32(bf16x8 a, bf16x8 b, f32x16 c) {
  return __builtin_amdgcn_mfma_f32_32x32x16_bf16(a, b, c, 0, 0, 0);
}

__global__ __launch_bounds__(512, 2)
void attn_fwd2(const __bf16* __restrict__ Q, const __bf16* __restrict__ Kk,
               const __bf16* __restrict__ Vt, __bf16* __restrict__ O) {
  __shared__ __bf16 Ks[2][64 * 64];   // [key][d], XOR-swizzled rows
  __shared__ __bf16 Vs[2][64 * 64];   // [d][key], XOR-swizzled rows

  const int tid = threadIdx.x;
  const int w = tid >> 6, lane = tid & 63;
  const int l31 = lane & 31, hi = lane >> 5;
  const int bh = blockIdx.x, b = bh >> 4, h = bh & 15;
  const int q0 = blockIdx.y * 256 + w * 32;

  // ---- Q fragments (B-operand: col=q=lane&31, k=d slice hi*8..), prescaled by 1/8
  bf16x8 qf[4];
  {
    const __bf16* qb = Q + (size_t)(b * SEQ + q0 + l31) * EMB + h * HDIM + hi * 8;
#pragma unroll
    for (int ks = 0; ks < 4; ++ks) {
      bf16x8 t = *(const bf16x8*)(qb + ks * 16);
#pragma unroll
      for (int j = 0; j < 8; ++j) t[j] = (__bf16)((float)t[j] * 0.125f);
      qf[ks] = t;
    }
  }

  // ---- staging addresses (pre-swizzled global source, linear LDS dest)
  const int srow = w * 8 + (lane >> 3);          // tile row this lane stages
  const int sswz = ((lane & 7) * 16) ^ ((srow & 7) << 4);
  const char* kg = (const char*)(Kk + (size_t)(b * SEQ) * EMB + h * HDIM)
                   + (size_t)srow * (EMB * 2) + sswz;
  const char* vg = (const char*)(Vt + (size_t)((b * NHEAD + h) * HDIM) * SEQ)
                   + (size_t)srow * (SEQ * 2) + sswz;

  auto STAGE = [&](int bi, int t) {
    gload_lds16(kg + (size_t)t * (64 * EMB * 2), (char*)&Ks[bi][0] + w * 1024);
    gload_lds16(vg + (size_t)t * 128,            (char*)&Vs[bi][0] + w * 1024);
  };

  f32x16 oacc0 = {}, oacc1 = {};
  float mx = -1e30f, ls = 0.f;
  const int rswz = (l31 & 7) << 4;

  STAGE(0, 0);
  for (int t = 0; t < 32; ++t) {
    const int bi = t & 1;
    if (t < 31) {
      STAGE(bi ^ 1, t + 1);
      asm volatile("s_waitcnt vmcnt(2)" ::: "memory");
    } else {
      asm volatile("s_waitcnt vmcnt(0)" ::: "memory");
    }
    __builtin_amdgcn_s_barrier();
    __builtin_amdgcn_sched_barrier(0);

    // ---- QK^T (swapped): sc[t] = K_tile . Q^T -> S^T[key][q]
    f32x16 sc0 = {}, sc1 = {};
    const char* kb = (const char*)&Ks[bi][0];
#pragma unroll
    for (int ks = 0; ks < 4; ++ks) {
      const int o = (ks * 32 + hi * 16) ^ rswz;
      bf16x8 k0 = *(const bf16x8*)(kb + l31 * 128 + o);
      bf16x8 k1 = *(const bf16x8*)(kb + (l31 + 32) * 128 + o);
      sc0 = mfma32(k0, qf[ks], sc0);
      sc1 = mfma32(k1, qf[ks], sc1);
    }

    // ---- online softmax, per-lane row q
    float pm = sc0[0];
#pragma unroll
    for (int r = 1; r < 16; ++r) pm = fmaxf(pm, sc0[r]);
#pragma unroll
    for (int r = 0; r < 16; ++r) pm = fmaxf(pm, sc1[r]);
    pm = fmaxf(pm, __shfl_xor(pm, 32));
    const float mn = fmaxf(mx, pm);
    const float corr = __expf(mx - mn);
    mx = mn;
    float rs = 0.f;
#pragma unroll
    for (int r = 0; r < 16; ++r) { sc0[r] = __expf(sc0[r] - mn); rs += sc0[r]; }
#pragma unroll
    for (int r = 0; r < 16; ++r) { sc1[r] = __expf(sc1[r] - mn); rs += sc1[r]; }
    rs += __shfl_xor(rs, 32);
    ls = ls * corr + rs;
#pragma unroll
    for (int r = 0; r < 16; ++r) { oacc0[r] *= corr; oacc1[r] *= corr; }

    // ---- P -> bf16 A-frags (P^T B-operand): pack pairs + lane^32 exchange
    union Fu { uint32_t w[4]; bf16x8 v; };
    auto pk = [](float a, float b) -> uint32_t {
      union { __bf16 h[2]; uint32_t u; } z;
      z.h[0] = (__bf16)a; z.h[1] = (__bf16)b; return z.u;
    };
    bf16x8 pa[4];
    {
      uint32_t A0 = pk(sc0[0], sc0[1]),  A1 = pk(sc0[2], sc0[3]);
      uint32_t B0 = pk(sc0[4], sc0[5]),  B1 = pk(sc0[6], sc0[7]);
      uint32_t C0 = pk(sc0[8], sc0[9]),  C1 = pk(sc0[10], sc0[11]);
      uint32_t D0 = pk(sc0[12], sc0[13]), D1 = pk(sc0[14], sc0[15]);
      uint32_t sA0 = __shfl_xor((int)A0, 32), sA1 = __shfl_xor((int)A1, 32);
      uint32_t sB0 = __shfl_xor((int)B0, 32), sB1 = __shfl_xor((int)B1, 32);
      uint32_t sC0 = __shfl_xor((int)C0, 32), sC1 = __shfl_xor((int)C1, 32);
      uint32_t sD0 = __shfl_xor((int)D0, 32), sD1 = __shfl_xor((int)D1, 32);
      Fu f0, f1;
      f0.w[0] = hi ? sB0 : A0;  f0.w[1] = hi ? sB1 : A1;
      f0.w[2] = hi ? B0 : sA0;  f0.w[3] = hi ? B1 : sA1;
      f1.w[0] = hi ? sD0 : C0;  f1.w[1] = hi ? sD1 : C1;
      f1.w[2] = hi ? D0 : sC0;  f1.w[3] = hi ? D1 : sC1;
      pa[0] = f0.v; pa[1] = f1.v;
      uint32_t E0 = pk(sc1[0], sc1[1]),  E1 = pk(sc1[2], sc1[3]);
      uint32_t F0 = pk(sc1[4], sc1[5]),  F1 = pk(sc1[6], sc1[7]);
      uint32_t G0 = pk(sc1[8], sc1[9]),  G1 = pk(sc1[10], sc1[11]);
      uint32_t H0 = pk(sc1[12], sc1[13]), H1 = pk(sc1[14], sc1[15]);
      uint32_t sE0 = __shfl_xor((int)E0, 32), sE1 = __shfl_xor((int)E1, 32);
      uint32_t sF0 = __shfl_xor((int)F0, 32), sF1 = __shfl_xor((int)F1, 32);
      uint32_t sG0 = __shfl_xor((int)G0, 32), sG1 = __shfl_xor((int)G1, 32);
      uint32_t sH0 = __shfl_xor((int)H0, 32), sH1 = __shfl_xor((int)H1, 32);
      Fu f2, f3;
      f2.w[0] = hi ? sF0 : E0;  f2.w[1] = hi ? sF1 : E1;
      f2.w[2] = hi ? F0 : sE0;  f2.w[3] = hi ? F1 : sE1;
      f3.w[0] = hi ? sH0 : G0;  f3.w[1] = hi ? sH1 : G1;
      f3.w[2] = hi ? H0 : sG0;  f3.w[3] = hi ? H1 : sG1;
      pa[2] = f2.v; pa[3] = f3.v;
    }

    // ---- PV (swapped): O^T += Vt_tile . P^T
    const char* vb = (const char*)&Vs[bi][0];
#pragma unroll
    for (int ks = 0; ks < 4; ++ks) {
      const int o = (ks * 32 + hi * 16) ^ rswz;
      bf16x8 v0 = *(const bf16x8*)(vb + l31 * 128 + o);
      bf16x8 v1 = *(const bf16x8*)(vb + (l31 + 32) * 128 + o);
      oacc0 = mfma32(v0, pa[ks], oacc0);
      oacc1 = mfma32(v1, pa[ks], oacc1);
    }

    __builtin_amdgcn_s_barrier();
    __builtin_amdgcn_sched_barrier(0);
  }

  // ---- normalize + store: lane holds O^T[d][q=q0+l31]; d = n*32 + 8c + 4hi + i
  const float inv = 1.f / ls;
  __bf16* ob = O + (size_t)(b * SEQ + q0 + l31) * EMB + h * HDIM;
#pragma unroll
  for (int c = 0; c < 4; ++c) {
    union { ushort4 u; __bf16 x[4]; } o0, o1;
#pragma unroll
    for (int i = 0; i < 4; ++i) {
      o0.x[i] = (__bf16)(oacc0[4 * c + i] * inv);
      o1.x[i] = (__bf16)(oacc1[4 * c + i] * inv);
    }
    *(ushort4*)(ob + 8 * c + 4 * hi)      = o0.u;
    *(ushort4*)(ob + 32 + 8 * c + 4 * hi) = o1.u;
  }
}

// ---------------- launch ----------------
extern "C" void kernel_launch(void* const* d_in, const int* in_sizes, int n_in,
                              void* d_out, int out_size, void* d_ws, size_t ws_size,
                              hipStream_t stream) {
  const float* query = (const float*)d_in[0];
  const float* key   = (const float*)d_in[1];
  const float* value = (const float*)d_in[2];
  const float* Wq = (const float*)d_in[3]; const float* bq = (const float*)d_in[4];
  const float* Wk = (const float*)d_in[5]; const float* bk = (const float*)d_in[6];
  const float* Wv = (const float*)d_in[7]; const float* bv = (const float*)d_in[8];
  const float* Wo = (const float*)d_in[9]; const float* bo = (const float*)d_in[10];

  char* ws = (char*)d_ws;
  const size_t MB = 1u << 20;
  __bf16* Xb  = (__bf16*)(ws);             // 16 MB staging (also reused for attn out)
  __bf16* Qb  = (__bf16*)(ws + 16 * MB);
  __bf16* Kb  = (__bf16*)(ws + 32 * MB);
  __bf16* Vt  = (__bf16*)(ws + 48 * MB);
  __bf16* Wqb = (__bf16*)(ws + 64 * MB);
  __bf16* Wkb = (__bf16*)(ws + 66 * MB);
  __bf16* Wvb = (__bf16*)(ws + 68 * MB);
  __bf16* Wob = (__bf16*)(ws + 70 * MB);

  const int NE = BATCH * SEQ * EMB;
  const int NW = EMB * EMB;
  const int M = BATCH * SEQ;

  dim3 blk(256);
  dim3 gg(M / 128, EMB / 128);

  cvt_f32_bf16<<<dim3(NW / 4 / 256), blk, 0, stream>>>(Wq, Wqb, NW / 4);
  cvt_f32_bf16<<<dim3(NW / 4 / 256), blk, 0, stream>>>(Wk, Wkb, NW / 4);
  cvt_f32_bf16<<<dim3(NW / 4 / 256), blk, 0, stream>>>(Wv, Wvb, NW / 4);
  cvt_f32_bf16<<<dim3(NW / 4 / 256), blk, 0, stream>>>(Wo, Wob, NW / 4);

  cvt_f32_bf16<<<dim3(NE / 4 / 256), blk, 0, stream>>>(query, Xb, NE / 4);
  gemm_bt<EPI_BF16><<<gg, blk, 0, stream>>>(Xb, Wqb, bq, Qb, M, EMB, EMB);
  cvt_f32_bf16<<<dim3(NE / 4 / 256), blk, 0, stream>>>(key, Xb, NE / 4);
  gemm_bt<EPI_BF16><<<gg, blk, 0, stream>>>(Xb, Wkb, bk, Kb, M, EMB, EMB);
  cvt_f32_bf16<<<dim3(NE / 4 / 256), blk, 0, stream>>>(value, Xb, NE / 4);
  gemm_bt<EPI_VT><<<gg, blk, 0, stream>>>(Xb, Wvb, bv, Vt, M, EMB, EMB);

  attn_fwd2<<<dim3(BATCH * NHEAD, SEQ / 256), dim3(512), 0, stream>>>(Qb, Kb, Vt, Xb);

  gemm_bt<EPI_F32><<<gg, blk, 0, stream>>>(Xb, Wob, bo, d_out, M, EMB, EMB);
}